// Round 1
// baseline (186.258 us; speedup 1.0000x reference)
//
#include <hip/hip_runtime.h>
#include <hip/hip_bf16.h>

typedef __bf16 bf16x8 __attribute__((ext_vector_type(8)));
typedef __bf16 bf16x4 __attribute__((ext_vector_type(4)));
typedef float  f32x4  __attribute__((ext_vector_type(4)));

#define MFMA_16x16x32(a,b,c) __builtin_amdgcn_mfma_f32_16x16x32_bf16((a),(b),(c),0,0,0)

static constexpr int DM = 768;
static constexpr int NH = 12;
static constexpr int HD = 64;
static constexpr int BB = 2;
static constexpr int SS = 2048;
static constexpr int NR = BB*SS;   // 4096 rows (b,s)
static constexpr int NC = 3*DM;    // 2304 qkv output cols
static constexpr float L2E = 1.4426950408889634f;

// ---------------- prep kernels ----------------
__global__ __launch_bounds__(256) void k_prep_x(const float* __restrict__ x,
                                                __bf16* __restrict__ xb){
  int i = blockIdx.x*256 + threadIdx.x;      // over NR*DM/4 elements
  float4 v = reinterpret_cast<const float4*>(x)[i];
  bf16x4 o; o[0]=(__bf16)v.x; o[1]=(__bf16)v.y; o[2]=(__bf16)v.z; o[3]=(__bf16)v.w;
  reinterpret_cast<bf16x4*>(xb)[i] = o;
}

// W{q,k,v}[h][d][e] -> Wt[c][d] bf16 (c = m*768 + h*64 + e), Wq scaled by 0.125
__global__ __launch_bounds__(256) void k_prep_wqkv(const float* __restrict__ Wq,
    const float* __restrict__ Wk, const float* __restrict__ Wv,
    __bf16* __restrict__ Wt){
  __shared__ float tile[64][65];
  int blk = blockIdx.x;
  int dt = blk % 12, h = (blk/12) % 12, m = blk/144;
  const float* W = (m==0)?Wq:((m==1)?Wk:Wv);
  float scale = (m==0)?0.125f:1.0f;
  int tx = threadIdx.x & 63, ty = threadIdx.x >> 6;
  #pragma unroll
  for (int i=0;i<16;i++){
    int dl = ty*16+i;
    tile[dl][tx] = W[(h*DM + dt*64 + dl)*HD + tx];   // tx = e (coalesced)
  }
  __syncthreads();
  #pragma unroll
  for (int i=0;i<16;i++){
    int e = ty*16+i;
    Wt[(size_t)(m*DM + h*HD + e)*DM + dt*64 + tx] = (__bf16)(tile[tx][e]*scale);
  }
}

// Wo[d][c] -> WoT[c][d] bf16
__global__ __launch_bounds__(256) void k_prep_wo(const float* __restrict__ Wo,
    __bf16* __restrict__ WoT){
  __shared__ float tile[64][65];
  int blk = blockIdx.x;
  int dt = blk % 12, ct = blk/12;
  int tx = threadIdx.x & 63, ty = threadIdx.x >> 6;
  #pragma unroll
  for (int i=0;i<16;i++){
    int dl = ty*16+i;
    tile[dl][tx] = Wo[(dt*64+dl)*DM + ct*64 + tx];
  }
  __syncthreads();
  #pragma unroll
  for (int i=0;i<16;i++){
    int cl = ty*16+i;
    WoT[(size_t)(ct*64+cl)*DM + dt*64 + tx] = (__bf16)tile[tx][cl];
  }
}

__global__ __launch_bounds__(256) void k_prep_bias(const float* __restrict__ bq,
    const float* __restrict__ bk, const float* __restrict__ bv,
    float* __restrict__ bqkv){
  int c = blockIdx.x*256 + threadIdx.x;
  if (c >= NC) return;
  int m = c/DM, r = c - m*DM;
  const float* s = (m==0)?bq:((m==1)?bk:bv);
  bqkv[c] = s[r] * ((m==0)?0.125f:1.0f);
}

// ---------------- GEMM: C = A[M,K] * Bt[N,K]^T + bias ----------------
// EPI==0: route cols to Q[bh][s][e] (scaled), K[bh][t][e], V^T[bh][e][t] (bf16)
// EPI==1: plain fp32 store to outF[M,768]
template<int BM, int EPI>
__global__ __launch_bounds__(256) void k_gemm(
    const __bf16* __restrict__ A, const __bf16* __restrict__ Bt,
    const float* __restrict__ bias, float* __restrict__ outF,
    __bf16* __restrict__ qb, __bf16* __restrict__ kb, __bf16* __restrict__ vt,
    int M, int N)
{
  constexpr int BN = 128, BK = 32, SKA = 40;   // SKA: pad 32->40 (80B rows, 16B aligned, conflict-free)
  constexpr int K = DM;
  constexpr int HM = BM/2;
  constexpr int MR = BM/32;
  __shared__ __align__(16) __bf16 As[BM][SKA];
  __shared__ __align__(16) __bf16 Bs[BN][SKA];
  const int tid = threadIdx.x;
  const int w = tid>>6, lane = tid&63, g = lane>>4, r15 = lane&15;
  const int wr = w>>1, wc = w&1;
  const int nTM = M/BM;
  const int mt = blockIdx.x % nTM, nt = blockIdx.x / nTM;
  const int m0 = mt*BM, n0 = nt*BN;

  f32x4 acc[MR][4];
  #pragma unroll
  for (int i=0;i<MR;i++)
    #pragma unroll
    for (int j=0;j<4;j++) acc[i][j] = f32x4{0.f,0.f,0.f,0.f};

  for (int k0=0;k0<K;k0+=BK){
    #pragma unroll
    for (int i=0;i<(BM*4)/256;i++){
      int chunk = tid + 256*i, row = chunk>>2, seg = chunk&3;
      *reinterpret_cast<uint4*>(&As[row][seg*8]) =
        *reinterpret_cast<const uint4*>(&A[(m0+row)*K + k0 + seg*8]);
    }
    #pragma unroll
    for (int i=0;i<2;i++){
      int chunk = tid + 256*i, row = chunk>>2, seg = chunk&3;
      *reinterpret_cast<uint4*>(&Bs[row][seg*8]) =
        *reinterpret_cast<const uint4*>(&Bt[(n0+row)*K + k0 + seg*8]);
    }
    __syncthreads();
    bf16x8 af[MR], bfr[4];
    #pragma unroll
    for (int mi=0;mi<MR;mi++)
      af[mi] = *reinterpret_cast<const bf16x8*>(&As[wr*HM + mi*16 + r15][g*8]);
    #pragma unroll
    for (int ni=0;ni<4;ni++)
      bfr[ni] = *reinterpret_cast<const bf16x8*>(&Bs[wc*64 + ni*16 + r15][g*8]);
    #pragma unroll
    for (int mi=0;mi<MR;mi++)
      #pragma unroll
      for (int ni=0;ni<4;ni++)
        acc[mi][ni] = MFMA_16x16x32(af[mi], bfr[ni], acc[mi][ni]);
    __syncthreads();
  }

  #pragma unroll
  for (int mi=0;mi<MR;mi++){
    #pragma unroll
    for (int ni=0;ni<4;ni++){
      int row0 = m0 + wr*HM + mi*16 + 4*g;      // D row = 4*(lane>>4)+reg
      int col  = n0 + wc*64 + ni*16 + r15;      // D col = lane&15
      float bc = bias[col];
      #pragma unroll
      for (int r=0;r<4;r++){
        float val = acc[mi][ni][r] + bc;
        int rr = row0 + r;
        if (EPI==1){
          outF[(size_t)rr*DM + col] = val;
        } else {
          int b = rr >> 11, s = rr & 2047;
          if (col < DM){
            int hh = col>>6, ee = col&63;
            qb[(((size_t)b*NH + hh)*SS + s)*HD + ee] = (__bf16)val;
          } else if (col < 2*DM){
            int c2 = col - DM, hh = c2>>6, ee = c2&63;
            kb[(((size_t)b*NH + hh)*SS + s)*HD + ee] = (__bf16)val;
          } else {
            int c2 = col - 2*DM, hh = c2>>6, ee = c2&63;
            vt[(((size_t)b*NH + hh)*HD + ee)*SS + s] = (__bf16)val;
          }
        }
      }
    }
  }
}

// ---------------- flash attention ----------------
// grid: (B*NH)*32 blocks; block = 4 waves; each wave owns 16 Q rows, block 64.
__global__ __launch_bounds__(256) void k_attn(
    const __bf16* __restrict__ Qb, const __bf16* __restrict__ Kb,
    const __bf16* __restrict__ Vt, __bf16* __restrict__ AO)
{
  constexpr int TT = 64, SK = 72;   // 144B LDS rows: 16B aligned, 2-way max conflicts
  __shared__ __align__(16) __bf16 Ks[TT][SK];
  __shared__ __align__(16) __bf16 Vs[HD][SK];
  __shared__ __align__(16) __bf16 Ps[4][16][SK];
  const int tid = threadIdx.x, w = tid>>6, lane = tid&63, g = lane>>4, r15 = lane&15;
  const int qt = blockIdx.x & 31, bh = blockIdx.x >> 5;
  const int q0 = qt*64;
  const __bf16* Qh = Qb + (size_t)bh*SS*HD;
  const __bf16* Kh = Kb + (size_t)bh*SS*HD;
  const __bf16* Vh = Vt + (size_t)bh*HD*SS;

  const int qrow = q0 + w*16 + r15;
  bf16x8 aq0 = *reinterpret_cast<const bf16x8*>(&Qh[qrow*HD + g*8]);
  bf16x8 aq1 = *reinterpret_cast<const bf16x8*>(&Qh[qrow*HD + 32 + g*8]);

  f32x4 o[4];
  #pragma unroll
  for (int i=0;i<4;i++) o[i] = f32x4{0.f,0.f,0.f,0.f};
  float mrow[4], lrow[4];
  #pragma unroll
  for (int r=0;r<4;r++){ mrow[r] = -3.0e38f; lrow[r] = 0.f; }

  for (int t0=0; t0<SS; t0+=TT){
    #pragma unroll
    for (int i=0;i<2;i++){
      int chunk = tid + 256*i, row = chunk>>3, seg = chunk&7;
      *reinterpret_cast<uint4*>(&Ks[row][seg*8]) =
        *reinterpret_cast<const uint4*>(&Kh[(t0+row)*HD + seg*8]);
    }
    #pragma unroll
    for (int i=0;i<2;i++){
      int chunk = tid + 256*i, row = chunk>>3, seg = chunk&7;
      *reinterpret_cast<uint4*>(&Vs[row][seg*8]) =
        *reinterpret_cast<const uint4*>(&Vh[row*SS + t0 + seg*8]);
    }
    __syncthreads();

    // scores: S = Qs * K^T  (16 x 64 per wave)
    f32x4 sc[4];
    #pragma unroll
    for (int jt=0;jt<4;jt++){
      sc[jt] = f32x4{0.f,0.f,0.f,0.f};
      bf16x8 kf0 = *reinterpret_cast<const bf16x8*>(&Ks[jt*16 + r15][g*8]);
      sc[jt] = MFMA_16x16x32(aq0, kf0, sc[jt]);
      bf16x8 kf1 = *reinterpret_cast<const bf16x8*>(&Ks[jt*16 + r15][32 + g*8]);
      sc[jt] = MFMA_16x16x32(aq1, kf1, sc[jt]);
    }

    // online softmax (rows 4g+r, reduce across the 16 lanes of the group)
    float tmax[4];
    #pragma unroll
    for (int r=0;r<4;r++)
      tmax[r] = fmaxf(fmaxf(sc[0][r], sc[1][r]), fmaxf(sc[2][r], sc[3][r]));
    #pragma unroll
    for (int msk=1; msk<16; msk<<=1)
      #pragma unroll
      for (int r=0;r<4;r++)
        tmax[r] = fmaxf(tmax[r], __shfl_xor(tmax[r], msk, 64));

    float mnew[4], fac[4], psum[4];
    #pragma unroll
    for (int r=0;r<4;r++){
      mnew[r] = fmaxf(mrow[r], tmax[r]);
      fac[r]  = exp2f((mrow[r]-mnew[r])*L2E);
      psum[r] = 0.f;
    }
    #pragma unroll
    for (int jt=0;jt<4;jt++)
      #pragma unroll
      for (int r=0;r<4;r++){
        float p = exp2f((sc[jt][r]-mnew[r])*L2E);
        psum[r] += p;
        Ps[w][4*g+r][jt*16 + r15] = (__bf16)p;
      }
    #pragma unroll
    for (int msk=1; msk<16; msk<<=1)
      #pragma unroll
      for (int r=0;r<4;r++)
        psum[r] += __shfl_xor(psum[r], msk, 64);
    #pragma unroll
    for (int r=0;r<4;r++){
      lrow[r] = lrow[r]*fac[r] + psum[r];
      mrow[r] = mnew[r];
    }
    #pragma unroll
    for (int et=0;et<4;et++)
      #pragma unroll
      for (int r=0;r<4;r++)
        o[et][r] *= fac[r];

    __syncthreads();   // safety: order Ps writes vs fragment reads across scheduler

    // PV: O += P * V   (P A-frags from per-wave LDS, V B-frags from Vs)
    bf16x8 pf0 = *reinterpret_cast<const bf16x8*>(&Ps[w][r15][g*8]);
    bf16x8 pf1 = *reinterpret_cast<const bf16x8*>(&Ps[w][r15][32 + g*8]);
    #pragma unroll
    for (int et=0;et<4;et++){
      bf16x8 v0 = *reinterpret_cast<const bf16x8*>(&Vs[et*16 + r15][g*8]);
      o[et] = MFMA_16x16x32(pf0, v0, o[et]);
      bf16x8 v1 = *reinterpret_cast<const bf16x8*>(&Vs[et*16 + r15][32 + g*8]);
      o[et] = MFMA_16x16x32(pf1, v1, o[et]);
    }
    __syncthreads();
  }

  const int b = bh/NH, h = bh - b*NH;
  const int srow0 = q0 + w*16 + 4*g;
  #pragma unroll
  for (int r=0;r<4;r++){
    float inv = 1.0f/lrow[r];
    int s = srow0 + r;
    #pragma unroll
    for (int et=0;et<4;et++){
      AO[((size_t)(b*SS + s))*DM + h*HD + et*16 + r15] = (__bf16)(o[et][r]*inv);
    }
  }
}

// ---------------- launch ----------------
extern "C" void kernel_launch(void* const* d_in, const int* in_sizes, int n_in,
                              void* d_out, int out_size, void* d_ws, size_t ws_size,
                              hipStream_t stream) {
  const float* x  = (const float*)d_in[0];
  const float* Wq = (const float*)d_in[1];
  const float* Wk = (const float*)d_in[2];
  const float* Wv = (const float*)d_in[3];
  const float* bq = (const float*)d_in[4];
  const float* bk = (const float*)d_in[5];
  const float* bv = (const float*)d_in[6];
  const float* Wo = (const float*)d_in[7];
  const float* bo = (const float*)d_in[8];
  float* out = (float*)d_out;

  char* ws = (char*)d_ws;
  size_t off = 0;
  auto alloc = [&](size_t bytes) -> void* {
    void* p = ws + off;
    off += (bytes + 255) & ~size_t(255);
    return p;
  };
  __bf16* xb   = (__bf16*)alloc((size_t)NR*DM*2);
  __bf16* wt   = (__bf16*)alloc((size_t)NC*DM*2);
  float*  bqkv = (float*) alloc((size_t)NC*4);
  __bf16* wot  = (__bf16*)alloc((size_t)DM*DM*2);
  __bf16* qb2  = (__bf16*)alloc((size_t)BB*NH*SS*HD*2);
  __bf16* kb2  = (__bf16*)alloc((size_t)BB*NH*SS*HD*2);
  __bf16* vt2  = (__bf16*)alloc((size_t)BB*NH*SS*HD*2);
  __bf16* aob  = (__bf16*)alloc((size_t)NR*DM*2);

  k_prep_x   <<<(NR*DM)/(4*256), 256, 0, stream>>>(x, xb);
  k_prep_wqkv<<<3*12*12, 256, 0, stream>>>(Wq, Wk, Wv, wt);
  k_prep_wo  <<<12*12, 256, 0, stream>>>(Wo, wot);
  k_prep_bias<<<(NC+255)/256, 256, 0, stream>>>(bq, bk, bv, bqkv);

  k_gemm<128,0><<<(NR/128)*(NC/128), 256, 0, stream>>>(
      xb, wt, bqkv, nullptr, qb2, kb2, vt2, NR, NC);

  k_attn<<<BB*NH*(SS/64), 256, 0, stream>>>(qb2, kb2, vt2, aob);

  k_gemm<64,1><<<(NR/64)*(DM/128), 256, 0, stream>>>(
      aob, wot, bo, out, nullptr, nullptr, nullptr, NR, DM);
}

// Round 2
// 166.377 us; speedup vs baseline: 1.1195x; 1.1195x over previous
//
#include <hip/hip_runtime.h>
#include <hip/hip_bf16.h>

typedef __bf16 bf16x8 __attribute__((ext_vector_type(8)));
typedef __bf16 bf16x4 __attribute__((ext_vector_type(4)));
typedef float  f32x4  __attribute__((ext_vector_type(4)));
typedef short  short4v __attribute__((ext_vector_type(4)));

#define MFMA_16x16x32(a,b,c) __builtin_amdgcn_mfma_f32_16x16x32_bf16((a),(b),(c),0,0,0)

// 16x16x16 bf16 MFMA: prefer gfx950 spelling, fall back to the gfx90a "_1k"
// spelling (same instruction, v4i16 operands), else inline asm.
#if __has_builtin(__builtin_amdgcn_mfma_f32_16x16x16_bf16)
__device__ inline f32x4 MFMA16(bf16x4 a, bf16x4 b, f32x4 c){
  return __builtin_amdgcn_mfma_f32_16x16x16_bf16(a, b, c, 0, 0, 0);
}
#elif __has_builtin(__builtin_amdgcn_mfma_f32_16x16x16bf16_1k)
__device__ inline f32x4 MFMA16(bf16x4 a, bf16x4 b, f32x4 c){
  return __builtin_amdgcn_mfma_f32_16x16x16bf16_1k(
      __builtin_bit_cast(short4v, a), __builtin_bit_cast(short4v, b), c, 0, 0, 0);
}
#else
__device__ inline f32x4 MFMA16(bf16x4 a, bf16x4 b, f32x4 c){
  f32x4 d;
  asm volatile("v_mfma_f32_16x16x16_bf16 %0, %1, %2, %3"
               : "=v"(d) : "v"(a), "v"(b), "v"(c));
  return d;
}
#endif

static constexpr int DM = 768;
static constexpr int NH = 12;
static constexpr int HD = 64;
static constexpr int BB = 2;
static constexpr int SS = 2048;
static constexpr int NR = BB*SS;   // 4096 rows (b,s)
static constexpr int NC = 3*DM;    // 2304 qkv output cols
// logits produced directly in log2 domain: fold 1/sqrt(64) * log2(e) into Wq,bq
static constexpr float SCALEQ = 0.125f * 1.4426950408889634f;

// ---------------- prep kernels ----------------
__global__ __launch_bounds__(256) void k_prep_x(const float* __restrict__ x,
                                                __bf16* __restrict__ xb){
  int i = blockIdx.x*256 + threadIdx.x;      // over NR*DM/4 elements
  float4 v = reinterpret_cast<const float4*>(x)[i];
  bf16x4 o; o[0]=(__bf16)v.x; o[1]=(__bf16)v.y; o[2]=(__bf16)v.z; o[3]=(__bf16)v.w;
  reinterpret_cast<bf16x4*>(xb)[i] = o;
}

// W{q,k,v}[h][d][e] -> Wt[c][d] bf16 (c = m*768 + h*64 + e), Wq scaled by SCALEQ
__global__ __launch_bounds__(256) void k_prep_wqkv(const float* __restrict__ Wq,
    const float* __restrict__ Wk, const float* __restrict__ Wv,
    __bf16* __restrict__ Wt){
  __shared__ float tile[64][65];
  int blk = blockIdx.x;
  int dt = blk % 12, h = (blk/12) % 12, m = blk/144;
  const float* W = (m==0)?Wq:((m==1)?Wk:Wv);
  float scale = (m==0)?SCALEQ:1.0f;
  int tx = threadIdx.x & 63, ty = threadIdx.x >> 6;
  #pragma unroll
  for (int i=0;i<16;i++){
    int dl = ty*16+i;
    tile[dl][tx] = W[(h*DM + dt*64 + dl)*HD + tx];   // tx = e (coalesced)
  }
  __syncthreads();
  #pragma unroll
  for (int i=0;i<16;i++){
    int e = ty*16+i;
    Wt[(size_t)(m*DM + h*HD + e)*DM + dt*64 + tx] = (__bf16)(tile[tx][e]*scale);
  }
}

// Wo[d][c] -> WoT[c][d] bf16
__global__ __launch_bounds__(256) void k_prep_wo(const float* __restrict__ Wo,
    __bf16* __restrict__ WoT){
  __shared__ float tile[64][65];
  int blk = blockIdx.x;
  int dt = blk % 12, ct = blk/12;
  int tx = threadIdx.x & 63, ty = threadIdx.x >> 6;
  #pragma unroll
  for (int i=0;i<16;i++){
    int dl = ty*16+i;
    tile[dl][tx] = Wo[(dt*64+dl)*DM + ct*64 + tx];
  }
  __syncthreads();
  #pragma unroll
  for (int i=0;i<16;i++){
    int cl = ty*16+i;
    WoT[(size_t)(ct*64+cl)*DM + dt*64 + tx] = (__bf16)tile[tx][cl];
  }
}

__global__ __launch_bounds__(256) void k_prep_bias(const float* __restrict__ bq,
    const float* __restrict__ bk, const float* __restrict__ bv,
    float* __restrict__ bqkv){
  int c = blockIdx.x*256 + threadIdx.x;
  if (c >= NC) return;
  int m = c/DM, r = c - m*DM;
  const float* s = (m==0)?bq:((m==1)?bk:bv);
  bqkv[c] = s[r] * ((m==0)?SCALEQ:1.0f);
}

// ---------------- GEMM: C = A[M,K] * Bt[N,K]^T + bias ----------------
template<int BM, int EPI>
__global__ __launch_bounds__(256) void k_gemm(
    const __bf16* __restrict__ A, const __bf16* __restrict__ Bt,
    const float* __restrict__ bias, float* __restrict__ outF,
    __bf16* __restrict__ qb, __bf16* __restrict__ kb, __bf16* __restrict__ vt,
    int M, int N)
{
  constexpr int BN = 128, BK = 32, SKA = 40;
  constexpr int K = DM;
  constexpr int HM = BM/2;
  constexpr int MR = BM/32;
  __shared__ __align__(16) __bf16 As[BM][SKA];
  __shared__ __align__(16) __bf16 Bs[BN][SKA];
  const int tid = threadIdx.x;
  const int w = tid>>6, lane = tid&63, g = lane>>4, r15 = lane&15;
  const int wr = w>>1, wc = w&1;
  const int nTM = M/BM;
  const int mt = blockIdx.x % nTM, nt = blockIdx.x / nTM;
  const int m0 = mt*BM, n0 = nt*BN;

  f32x4 acc[MR][4];
  #pragma unroll
  for (int i=0;i<MR;i++)
    #pragma unroll
    for (int j=0;j<4;j++) acc[i][j] = f32x4{0.f,0.f,0.f,0.f};

  for (int k0=0;k0<K;k0+=BK){
    #pragma unroll
    for (int i=0;i<(BM*4)/256;i++){
      int chunk = tid + 256*i, row = chunk>>2, seg = chunk&3;
      *reinterpret_cast<uint4*>(&As[row][seg*8]) =
        *reinterpret_cast<const uint4*>(&A[(m0+row)*K + k0 + seg*8]);
    }
    #pragma unroll
    for (int i=0;i<2;i++){
      int chunk = tid + 256*i, row = chunk>>2, seg = chunk&3;
      *reinterpret_cast<uint4*>(&Bs[row][seg*8]) =
        *reinterpret_cast<const uint4*>(&Bt[(n0+row)*K + k0 + seg*8]);
    }
    __syncthreads();
    bf16x8 af[MR], bfr[4];
    #pragma unroll
    for (int mi=0;mi<MR;mi++)
      af[mi] = *reinterpret_cast<const bf16x8*>(&As[wr*HM + mi*16 + r15][g*8]);
    #pragma unroll
    for (int ni=0;ni<4;ni++)
      bfr[ni] = *reinterpret_cast<const bf16x8*>(&Bs[wc*64 + ni*16 + r15][g*8]);
    #pragma unroll
    for (int mi=0;mi<MR;mi++)
      #pragma unroll
      for (int ni=0;ni<4;ni++)
        acc[mi][ni] = MFMA_16x16x32(af[mi], bfr[ni], acc[mi][ni]);
    __syncthreads();
  }

  #pragma unroll
  for (int mi=0;mi<MR;mi++){
    #pragma unroll
    for (int ni=0;ni<4;ni++){
      int row0 = m0 + wr*HM + mi*16 + 4*g;
      int col  = n0 + wc*64 + ni*16 + r15;
      float bc = bias[col];
      #pragma unroll
      for (int r=0;r<4;r++){
        float val = acc[mi][ni][r] + bc;
        int rr = row0 + r;
        if (EPI==1){
          outF[(size_t)rr*DM + col] = val;
        } else {
          int b = rr >> 11, s = rr & 2047;
          if (col < DM){
            int hh = col>>6, ee = col&63;
            qb[(((size_t)b*NH + hh)*SS + s)*HD + ee] = (__bf16)val;
          } else if (col < 2*DM){
            int c2 = col - DM, hh = c2>>6, ee = c2&63;
            kb[(((size_t)b*NH + hh)*SS + s)*HD + ee] = (__bf16)val;
          } else {
            int c2 = col - 2*DM, hh = c2>>6, ee = c2&63;
            vt[(((size_t)b*NH + hh)*HD + ee)*SS + s] = (__bf16)val;
          }
        }
      }
    }
  }
}

// ---------------- flash attention (swapped-QK^T, zero-shuffle P) ----------------
// grid: (B*NH)*(S/128) blocks; 4 waves/block; each wave owns 32 q rows (2 subtiles).
// QK^T: mfma(K,Q) -> lane holds P[k=16jt+4g+r][q=r15]: 16 k-values for one q-row.
// Those 4 regs per 16-k step ARE the A-frag of mfma_f32_16x16x16_bf16 for PV.
__global__ __launch_bounds__(256) void k_attn(
    const __bf16* __restrict__ Qb, const __bf16* __restrict__ Kb,
    const __bf16* __restrict__ Vt, __bf16* __restrict__ AO)
{
  constexpr int TT = 64, SK = 72;    // 144B LDS rows
  __shared__ __align__(16) __bf16 Ks[2][TT][SK];
  __shared__ __align__(16) __bf16 Vs[2][HD][SK];   // permuted-col V^T tile
  const int tid = threadIdx.x, w = tid>>6, lane = tid&63, g = lane>>4, r15 = lane&15;
  const int qt = blockIdx.x & 15, bh = blockIdx.x >> 4;
  const int q0 = qt*128 + w*32;     // wave's 32 q-rows
  const __bf16* Qh = Qb + (size_t)bh*SS*HD;
  const __bf16* Kh = Kb + (size_t)bh*SS*HD;
  const __bf16* Vh = Vt + (size_t)bh*HD*SS;

  // Q B-fragments for both 16-row subtiles (log2-domain scale already folded)
  bf16x8 qf[2][2];
  #pragma unroll
  for (int sub=0; sub<2; sub++){
    int qrow = q0 + sub*16 + r15;
    qf[sub][0] = *reinterpret_cast<const bf16x8*>(&Qh[qrow*HD + g*8]);
    qf[sub][1] = *reinterpret_cast<const bf16x8*>(&Qh[qrow*HD + 32 + g*8]);
  }

  f32x4 o[2][4];
  #pragma unroll
  for (int s2=0;s2<2;s2++)
    #pragma unroll
    for (int i=0;i<4;i++) o[s2][i] = f32x4{0.f,0.f,0.f,0.f};
  float mst[2] = {-1.0e30f, -1.0e30f};
  float lst[2] = {0.f, 0.f};

  // staging geometry: chunk c in [0,512): row=c>>3, seg=c&7 (16B per chunk)
  const int row0 = tid>>3,        seg0 = tid&7;
  const int row1 = (tid+256)>>3,  seg1 = tid&7;
  // permuted V col for seg s, first half: col0 = 32*(s>>2)+16*(s&1)+4*((s>>1)&1)
  const int vcol0 = 32*(seg0>>2) + 16*(seg0&1) + 4*((seg0>>1)&1);

  // prologue: stage tile 0 into buffer 0
  {
    uint4 k0v = *reinterpret_cast<const uint4*>(&Kh[row0*HD + seg0*8]);
    uint4 k1v = *reinterpret_cast<const uint4*>(&Kh[row1*HD + seg1*8]);
    uint4 v0v = *reinterpret_cast<const uint4*>(&Vh[(size_t)row0*SS + seg0*8]);
    uint4 v1v = *reinterpret_cast<const uint4*>(&Vh[(size_t)row1*SS + seg1*8]);
    *reinterpret_cast<uint4*>(&Ks[0][row0][seg0*8]) = k0v;
    *reinterpret_cast<uint4*>(&Ks[0][row1][seg1*8]) = k1v;
    *reinterpret_cast<uint2*>(&Vs[0][row0][vcol0])     = uint2{v0v.x, v0v.y};
    *reinterpret_cast<uint2*>(&Vs[0][row0][vcol0 + 8]) = uint2{v0v.z, v0v.w};
    *reinterpret_cast<uint2*>(&Vs[0][row1][vcol0])     = uint2{v1v.x, v1v.y};
    *reinterpret_cast<uint2*>(&Vs[0][row1][vcol0 + 8]) = uint2{v1v.z, v1v.w};
  }
  __syncthreads();

  int cur = 0;
  for (int t0 = 0; t0 < SS; t0 += TT){
    const bool hasNext = (t0 + TT) < SS;
    uint4 k0v, k1v, v0v, v1v;
    if (hasNext){   // issue next-tile global loads early; write to LDS late
      k0v = *reinterpret_cast<const uint4*>(&Kh[(t0+TT+row0)*HD + seg0*8]);
      k1v = *reinterpret_cast<const uint4*>(&Kh[(t0+TT+row1)*HD + seg1*8]);
      v0v = *reinterpret_cast<const uint4*>(&Vh[(size_t)row0*SS + t0+TT + seg0*8]);
      v1v = *reinterpret_cast<const uint4*>(&Vh[(size_t)row1*SS + t0+TT + seg1*8]);
    }

    // K fragments (A-operand) and V fragments (B-operand, b128 spanning 2 k-steps)
    bf16x8 kf0[4], kf1[4];
    #pragma unroll
    for (int jt=0;jt<4;jt++){
      kf0[jt] = *reinterpret_cast<const bf16x8*>(&Ks[cur][jt*16 + r15][g*8]);
      kf1[jt] = *reinterpret_cast<const bf16x8*>(&Ks[cur][jt*16 + r15][32 + g*8]);
    }
    bf16x8 vf[4][2];
    #pragma unroll
    for (int et=0;et<4;et++)
      #pragma unroll
      for (int p=0;p<2;p++)
        vf[et][p] = *reinterpret_cast<const bf16x8*>(&Vs[cur][et*16 + r15][p*32 + g*8]);

    // QK^T swapped: sc[sub][jt] = D[k=4g+r (within jt*16)][q=r15]
    f32x4 sc[2][4];
    #pragma unroll
    for (int sub=0; sub<2; sub++)
      #pragma unroll
      for (int jt=0;jt<4;jt++){
        f32x4 t = f32x4{0.f,0.f,0.f,0.f};
        t = MFMA_16x16x32(kf0[jt], qf[sub][0], t);
        t = MFMA_16x16x32(kf1[jt], qf[sub][1], t);
        sc[sub][jt] = t;
      }

    // online softmax, fully in-register; defer-max (THR=8, log2 domain)
    bf16x4 pa[2][4];
    #pragma unroll
    for (int sub=0; sub<2; sub++){
      float tmax = sc[sub][0][0];
      #pragma unroll
      for (int jt=0;jt<4;jt++)
        #pragma unroll
        for (int r=0;r<4;r++) tmax = fmaxf(tmax, sc[sub][jt][r]);
      tmax = fmaxf(tmax, __shfl_xor(tmax, 16));
      tmax = fmaxf(tmax, __shfl_xor(tmax, 32));
      if (!__all(tmax <= mst[sub] + 8.0f)){
        float mn  = fmaxf(mst[sub], tmax);
        float fac = exp2f(mst[sub] - mn);
        mst[sub] = mn;
        lst[sub] *= fac;
        float fo0 = __shfl(fac, 4*g+0), fo1 = __shfl(fac, 4*g+1);
        float fo2 = __shfl(fac, 4*g+2), fo3 = __shfl(fac, 4*g+3);
        #pragma unroll
        for (int et=0;et<4;et++){
          o[sub][et][0] *= fo0; o[sub][et][1] *= fo1;
          o[sub][et][2] *= fo2; o[sub][et][3] *= fo3;
        }
      }
      float ps = 0.f;
      #pragma unroll
      for (int ks=0;ks<4;ks++){
        float p0 = exp2f(sc[sub][ks][0] - mst[sub]);
        float p1 = exp2f(sc[sub][ks][1] - mst[sub]);
        float p2 = exp2f(sc[sub][ks][2] - mst[sub]);
        float p3 = exp2f(sc[sub][ks][3] - mst[sub]);
        ps += (p0 + p1) + (p2 + p3);
        pa[sub][ks][0] = (__bf16)p0; pa[sub][ks][1] = (__bf16)p1;
        pa[sub][ks][2] = (__bf16)p2; pa[sub][ks][3] = (__bf16)p3;
      }
      lst[sub] += ps;   // per-lane partial; cross-g reduced once at the end
    }

    if (hasNext){   // LDS writes for next tile (waits vmcnt internally)
      int nxt = cur ^ 1;
      *reinterpret_cast<uint4*>(&Ks[nxt][row0][seg0*8]) = k0v;
      *reinterpret_cast<uint4*>(&Ks[nxt][row1][seg1*8]) = k1v;
      *reinterpret_cast<uint2*>(&Vs[nxt][row0][vcol0])     = uint2{v0v.x, v0v.y};
      *reinterpret_cast<uint2*>(&Vs[nxt][row0][vcol0 + 8]) = uint2{v0v.z, v0v.w};
      *reinterpret_cast<uint2*>(&Vs[nxt][row1][vcol0])     = uint2{v1v.x, v1v.y};
      *reinterpret_cast<uint2*>(&Vs[nxt][row1][vcol0 + 8]) = uint2{v1v.z, v1v.w};
    }

    // PV: O[q=4g+r][e=et*16+r15] += P * V  (P regs feed MFMA16 A directly)
    #pragma unroll
    for (int sub=0; sub<2; sub++)
      #pragma unroll
      for (int et=0;et<4;et++)
        #pragma unroll
        for (int ks=0;ks<4;ks++){
          bf16x8 vv = vf[et][ks>>1];
          bf16x4 vq = (ks & 1) ? bf16x4{vv[4],vv[5],vv[6],vv[7]}
                               : bf16x4{vv[0],vv[1],vv[2],vv[3]};
          o[sub][et] = MFMA16(pa[sub][ks], vq, o[sub][et]);
        }

    __syncthreads();
    cur ^= 1;
  }

  // finalize: full l via cross-g reduce (m is g-uniform), then normalize+store
  const int b = bh/NH, h = bh - b*NH;
  #pragma unroll
  for (int sub=0; sub<2; sub++){
    float lv = lst[sub];
    lv += __shfl_xor(lv, 16);
    lv += __shfl_xor(lv, 32);
    float linv = 1.0f / lv;
    float li0 = __shfl(linv, 4*g+0), li1 = __shfl(linv, 4*g+1);
    float li2 = __shfl(linv, 4*g+2), li3 = __shfl(linv, 4*g+3);
    float li[4] = {li0, li1, li2, li3};
    #pragma unroll
    for (int r=0;r<4;r++){
      int s = q0 + sub*16 + 4*g + r;
      #pragma unroll
      for (int et=0;et<4;et++){
        AO[((size_t)(b*SS + s))*DM + h*HD + et*16 + r15] = (__bf16)(o[sub][et][r]*li[r]);
      }
    }
  }
}

// ---------------- launch ----------------
extern "C" void kernel_launch(void* const* d_in, const int* in_sizes, int n_in,
                              void* d_out, int out_size, void* d_ws, size_t ws_size,
                              hipStream_t stream) {
  const float* x  = (const float*)d_in[0];
  const float* Wq = (const float*)d_in[1];
  const float* Wk = (const float*)d_in[2];
  const float* Wv = (const float*)d_in[3];
  const float* bq = (const float*)d_in[4];
  const float* bk = (const float*)d_in[5];
  const float* bv = (const float*)d_in[6];
  const float* Wo = (const float*)d_in[7];
  const float* bo = (const float*)d_in[8];
  float* out = (float*)d_out;

  char* ws = (char*)d_ws;
  size_t off = 0;
  auto alloc = [&](size_t bytes) -> void* {
    void* p = ws + off;
    off += (bytes + 255) & ~size_t(255);
    return p;
  };
  __bf16* xb   = (__bf16*)alloc((size_t)NR*DM*2);
  __bf16* wt   = (__bf16*)alloc((size_t)NC*DM*2);
  float*  bqkv = (float*) alloc((size_t)NC*4);
  __bf16* wot  = (__bf16*)alloc((size_t)DM*DM*2);
  __bf16* qb2  = (__bf16*)alloc((size_t)BB*NH*SS*HD*2);
  __bf16* kb2  = (__bf16*)alloc((size_t)BB*NH*SS*HD*2);
  __bf16* vt2  = (__bf16*)alloc((size_t)BB*NH*SS*HD*2);
  __bf16* aob  = (__bf16*)alloc((size_t)NR*DM*2);

  k_prep_x   <<<(NR*DM)/(4*256), 256, 0, stream>>>(x, xb);
  k_prep_wqkv<<<3*12*12, 256, 0, stream>>>(Wq, Wk, Wv, wt);
  k_prep_wo  <<<12*12, 256, 0, stream>>>(Wo, wot);
  k_prep_bias<<<(NC+255)/256, 256, 0, stream>>>(bq, bk, bv, bqkv);

  k_gemm<128,0><<<(NR/128)*(NC/128), 256, 0, stream>>>(
      xb, wt, bqkv, nullptr, qb2, kb2, vt2, NR, NC);

  k_attn<<<BB*NH*(SS/128), 256, 0, stream>>>(qb2, kb2, vt2, aob);

  k_gemm<64,1><<<(NR/64)*(DM/128), 256, 0, stream>>>(
      aob, wot, bo, out, nullptr, nullptr, nullptr, NR, DM);
}

// Round 3
// 143.935 us; speedup vs baseline: 1.2940x; 1.1559x over previous
//
#include <hip/hip_runtime.h>
#include <hip/hip_bf16.h>

typedef __bf16 bf16x8 __attribute__((ext_vector_type(8)));
typedef __bf16 bf16x4 __attribute__((ext_vector_type(4)));
typedef float  f32x4  __attribute__((ext_vector_type(4)));
typedef short  short4v __attribute__((ext_vector_type(4)));

#define MFMA_16x16x32(a,b,c) __builtin_amdgcn_mfma_f32_16x16x32_bf16((a),(b),(c),0,0,0)

#if __has_builtin(__builtin_amdgcn_mfma_f32_16x16x16_bf16)
__device__ inline f32x4 MFMA16(bf16x4 a, bf16x4 b, f32x4 c){
  return __builtin_amdgcn_mfma_f32_16x16x16_bf16(a, b, c, 0, 0, 0);
}
#elif __has_builtin(__builtin_amdgcn_mfma_f32_16x16x16bf16_1k)
__device__ inline f32x4 MFMA16(bf16x4 a, bf16x4 b, f32x4 c){
  return __builtin_amdgcn_mfma_f32_16x16x16bf16_1k(
      __builtin_bit_cast(short4v, a), __builtin_bit_cast(short4v, b), c, 0, 0, 0);
}
#else
__device__ inline f32x4 MFMA16(bf16x4 a, bf16x4 b, f32x4 c){
  f32x4 d;
  asm volatile("v_mfma_f32_16x16x16_bf16 %0, %1, %2, %3"
               : "=v"(d) : "v"(a), "v"(b), "v"(c));
  return d;
}
#endif

#if __has_builtin(__builtin_amdgcn_global_load_lds)
#define HAS_GLDS 1
__device__ inline void glds16(const __bf16* g, __bf16* l){
  __builtin_amdgcn_global_load_lds(
      (const __attribute__((address_space(1))) unsigned int*)g,
      (__attribute__((address_space(3))) unsigned int*)l, 16, 0, 0);
}
#else
#define HAS_GLDS 0
#endif

static constexpr int DM = 768;
static constexpr int NH = 12;
static constexpr int HD = 64;
static constexpr int BB = 2;
static constexpr int SS = 2048;
static constexpr int NR = BB*SS;     // 4096 rows (b,s)
static constexpr int NC = 3*DM;      // 2304 qkv output cols
static constexpr int RTOT = BB*NH*SS;  // 49152 (bh,s) rows
// logits in log2 domain: fold 1/sqrt(64) * log2(e) into Wq,bq
static constexpr float SCALEQ = 0.125f * 1.4426950408889634f;

// ---------------- prep kernels ----------------
__global__ __launch_bounds__(256) void k_prep_x(const float* __restrict__ x,
                                                __bf16* __restrict__ xb){
  int i = blockIdx.x*256 + threadIdx.x;
  float4 v = reinterpret_cast<const float4*>(x)[i];
  bf16x4 o; o[0]=(__bf16)v.x; o[1]=(__bf16)v.y; o[2]=(__bf16)v.z; o[3]=(__bf16)v.w;
  reinterpret_cast<bf16x4*>(xb)[i] = o;
}

__global__ __launch_bounds__(256) void k_prep_wqkv(const float* __restrict__ Wq,
    const float* __restrict__ Wk, const float* __restrict__ Wv,
    __bf16* __restrict__ Wt){
  __shared__ float tile[64][65];
  int blk = blockIdx.x;
  int dt = blk % 12, h = (blk/12) % 12, m = blk/144;
  const float* W = (m==0)?Wq:((m==1)?Wk:Wv);
  float scale = (m==0)?SCALEQ:1.0f;
  int tx = threadIdx.x & 63, ty = threadIdx.x >> 6;
  #pragma unroll
  for (int i=0;i<16;i++){
    int dl = ty*16+i;
    tile[dl][tx] = W[(h*DM + dt*64 + dl)*HD + tx];
  }
  __syncthreads();
  #pragma unroll
  for (int i=0;i<16;i++){
    int e = ty*16+i;
    Wt[(size_t)(m*DM + h*HD + e)*DM + dt*64 + tx] = (__bf16)(tile[tx][e]*scale);
  }
}

__global__ __launch_bounds__(256) void k_prep_wo(const float* __restrict__ Wo,
    __bf16* __restrict__ WoT){
  __shared__ float tile[64][65];
  int blk = blockIdx.x;
  int dt = blk % 12, ct = blk/12;
  int tx = threadIdx.x & 63, ty = threadIdx.x >> 6;
  #pragma unroll
  for (int i=0;i<16;i++){
    int dl = ty*16+i;
    tile[dl][tx] = Wo[(dt*64+dl)*DM + ct*64 + tx];
  }
  __syncthreads();
  #pragma unroll
  for (int i=0;i<16;i++){
    int cl = ty*16+i;
    WoT[(size_t)(ct*64+cl)*DM + dt*64 + tx] = (__bf16)tile[tx][cl];
  }
}

__global__ __launch_bounds__(256) void k_prep_bias(const float* __restrict__ bq,
    const float* __restrict__ bk, const float* __restrict__ bv,
    float* __restrict__ bqkv){
  int c = blockIdx.x*256 + threadIdx.x;
  if (c >= NC) return;
  int m = c/DM, r = c - m*DM;
  const float* s = (m==0)?bq:((m==1)?bk:bv);
  bqkv[c] = s[r] * ((m==0)?SCALEQ:1.0f);
}

// ---------------- GEMM: C = A[M,K] * Bt[N,K]^T + bias ----------------
// m97 pattern: global_load_lds width=16 into linear LDS [BM][64] with XOR
// column swizzle (source pre-swizzled, reads apply same XOR -> 2-way max).
template<int BM, int EPI>
__global__ __launch_bounds__(256) void k_gemm(
    const __bf16* __restrict__ A, const __bf16* __restrict__ Bt,
    const float* __restrict__ bias, float* __restrict__ outF,
    __bf16* __restrict__ qb, __bf16* __restrict__ kb, __bf16* __restrict__ vt,
    int M, int N)
{
  constexpr int BN = 128, BK = 64;
  constexpr int K = DM;
  constexpr int HM = BM/2;
  constexpr int MR = BM/32;
  __shared__ __align__(16) __bf16 As[BM][BK];
  __shared__ __align__(16) __bf16 Bs[BN][BK];
  const int tid = threadIdx.x;
  const int w = tid>>6, lane = tid&63, g = lane>>4, r15 = lane&15;
  const int wr = w>>1, wc = w&1;
  const int nTM = M/BM;
  const int mt = blockIdx.x % nTM, nt = blockIdx.x / nTM;
  const int m0 = mt*BM, n0 = nt*BN;

  // staging: 8 segs of 16B per 128B row; 8 rows per wave-call (1024B)
  const int rrel = lane>>3, seg = lane&7;
  const int ssrc = seg ^ rrel;            // XOR-swizzled source column

  f32x4 acc[MR][4];
  #pragma unroll
  for (int i=0;i<MR;i++)
    #pragma unroll
    for (int j=0;j<4;j++) acc[i][j] = f32x4{0.f,0.f,0.f,0.f};

  for (int k0=0;k0<K;k0+=BK){
#if HAS_GLDS
    #pragma unroll
    for (int c=0;c<BM/32;c++)
      glds16(&A[(size_t)(m0 + w*(BM/4) + c*8 + rrel)*K + k0 + ssrc*8],
             &As[w*(BM/4) + c*8][0]);
    #pragma unroll
    for (int c=0;c<4;c++)
      glds16(&Bt[(size_t)(n0 + w*32 + c*8 + rrel)*K + k0 + ssrc*8],
             &Bs[w*32 + c*8][0]);
#else
    #pragma unroll
    for (int c=0;c<BM/32;c++)
      *reinterpret_cast<uint4*>(&As[w*(BM/4) + c*8 + rrel][seg*8]) =
        *reinterpret_cast<const uint4*>(&A[(size_t)(m0 + w*(BM/4) + c*8 + rrel)*K + k0 + ssrc*8]);
    #pragma unroll
    for (int c=0;c<4;c++)
      *reinterpret_cast<uint4*>(&Bs[w*32 + c*8 + rrel][seg*8]) =
        *reinterpret_cast<const uint4*>(&Bt[(size_t)(n0 + w*32 + c*8 + rrel)*K + k0 + ssrc*8]);
#endif
    __syncthreads();
    bf16x8 af[MR][2], bfr[4][2];
    #pragma unroll
    for (int mi=0;mi<MR;mi++){
      int row = wr*HM + mi*16 + r15;
      #pragma unroll
      for (int c2=0;c2<2;c2++)
        af[mi][c2] = *reinterpret_cast<const bf16x8*>(&As[row][8*((c2*4+g) ^ (row&7))]);
    }
    #pragma unroll
    for (int ni=0;ni<4;ni++){
      int row = wc*64 + ni*16 + r15;
      #pragma unroll
      for (int c2=0;c2<2;c2++)
        bfr[ni][c2] = *reinterpret_cast<const bf16x8*>(&Bs[row][8*((c2*4+g) ^ (row&7))]);
    }
    #pragma unroll
    for (int c2=0;c2<2;c2++)
      #pragma unroll
      for (int mi=0;mi<MR;mi++)
        #pragma unroll
        for (int ni=0;ni<4;ni++)
          acc[mi][ni] = MFMA_16x16x32(af[mi][c2], bfr[ni][c2], acc[mi][ni]);
    __syncthreads();
  }

  #pragma unroll
  for (int mi=0;mi<MR;mi++){
    #pragma unroll
    for (int ni=0;ni<4;ni++){
      int row0 = m0 + wr*HM + mi*16 + 4*g;
      int col  = n0 + wc*64 + ni*16 + r15;
      float bc = bias[col];
      #pragma unroll
      for (int r=0;r<4;r++){
        float val = acc[mi][ni][r] + bc;
        int rr = row0 + r;
        if (EPI==1){
          outF[(size_t)rr*DM + col] = val;
        } else {
          int b = rr >> 11, s = rr & 2047;
          if (col < DM){
            int hh = col>>6, ee = col&63;
            qb[(((size_t)b*NH + hh)*SS + s)*HD + ee] = (__bf16)val;
          } else if (col < 2*DM){
            int c2 = col - DM, hh = c2>>6, ee = c2&63;
            kb[(((size_t)b*NH + hh)*SS + s)*HD + ee] = (__bf16)val;
          } else {
            int c2 = col - 2*DM, hh = c2>>6, ee = c2&63;
            vt[(((size_t)b*NH + hh)*HD + ee)*SS + s] = (__bf16)val;
          }
        }
      }
    }
  }
}

// ---------------- flash attention (swapped-QK^T, KV-split) ----------------
// grid: x = (B*NH)*(S/128), y = nsplit. Each block: 128 q rows x kvLen keys.
// nsplit>1: store unnormalized O (f32) + per-row m,l partials; merged later.
__global__ __launch_bounds__(256) void k_attn(
    const __bf16* __restrict__ Qb, const __bf16* __restrict__ Kb,
    const __bf16* __restrict__ Vt, float* __restrict__ oP,
    float* __restrict__ mP, float* __restrict__ lP,
    __bf16* __restrict__ AO, int kvLen)
{
  constexpr int TT = 64, SK = 72;
  __shared__ __align__(16) __bf16 Ks[2][TT][SK];
  __shared__ __align__(16) __bf16 Vs[2][HD][SK];
  const int tid = threadIdx.x, w = tid>>6, lane = tid&63, g = lane>>4, r15 = lane&15;
  const int qt = blockIdx.x & 15, bh = blockIdx.x >> 4;
  const int q0 = qt*128 + w*32;
  const int kv0 = blockIdx.y * kvLen;
  const __bf16* Qh = Qb + (size_t)bh*SS*HD;
  const __bf16* Kh = Kb + (size_t)bh*SS*HD;
  const __bf16* Vh = Vt + (size_t)bh*HD*SS;

  bf16x8 qf[2][2];
  #pragma unroll
  for (int sub=0; sub<2; sub++){
    int qrow = q0 + sub*16 + r15;
    qf[sub][0] = *reinterpret_cast<const bf16x8*>(&Qh[qrow*HD + g*8]);
    qf[sub][1] = *reinterpret_cast<const bf16x8*>(&Qh[qrow*HD + 32 + g*8]);
  }

  f32x4 o[2][4];
  #pragma unroll
  for (int s2=0;s2<2;s2++)
    #pragma unroll
    for (int i=0;i<4;i++) o[s2][i] = f32x4{0.f,0.f,0.f,0.f};
  float mst[2] = {-1.0e30f, -1.0e30f};
  float lst[2] = {0.f, 0.f};

  const int row0 = tid>>3,        seg0 = tid&7;
  const int row1 = (tid+256)>>3,  seg1 = tid&7;
  const int vcol0 = 32*(seg0>>2) + 16*(seg0&1) + 4*((seg0>>1)&1);

  {
    uint4 k0v = *reinterpret_cast<const uint4*>(&Kh[(kv0+row0)*HD + seg0*8]);
    uint4 k1v = *reinterpret_cast<const uint4*>(&Kh[(kv0+row1)*HD + seg1*8]);
    uint4 v0v = *reinterpret_cast<const uint4*>(&Vh[(size_t)row0*SS + kv0 + seg0*8]);
    uint4 v1v = *reinterpret_cast<const uint4*>(&Vh[(size_t)row1*SS + kv0 + seg1*8]);
    *reinterpret_cast<uint4*>(&Ks[0][row0][seg0*8]) = k0v;
    *reinterpret_cast<uint4*>(&Ks[0][row1][seg1*8]) = k1v;
    *reinterpret_cast<uint2*>(&Vs[0][row0][vcol0])     = uint2{v0v.x, v0v.y};
    *reinterpret_cast<uint2*>(&Vs[0][row0][vcol0 + 8]) = uint2{v0v.z, v0v.w};
    *reinterpret_cast<uint2*>(&Vs[0][row1][vcol0])     = uint2{v1v.x, v1v.y};
    *reinterpret_cast<uint2*>(&Vs[0][row1][vcol0 + 8]) = uint2{v1v.z, v1v.w};
  }
  __syncthreads();

  int cur = 0;
  for (int t0 = kv0; t0 < kv0 + kvLen; t0 += TT){
    const bool hasNext = (t0 + TT) < kv0 + kvLen;
    uint4 k0v, k1v, v0v, v1v;
    if (hasNext){
      k0v = *reinterpret_cast<const uint4*>(&Kh[(t0+TT+row0)*HD + seg0*8]);
      k1v = *reinterpret_cast<const uint4*>(&Kh[(t0+TT+row1)*HD + seg1*8]);
      v0v = *reinterpret_cast<const uint4*>(&Vh[(size_t)row0*SS + t0+TT + seg0*8]);
      v1v = *reinterpret_cast<const uint4*>(&Vh[(size_t)row1*SS + t0+TT + seg1*8]);
    }

    bf16x8 kf0[4], kf1[4];
    #pragma unroll
    for (int jt=0;jt<4;jt++){
      kf0[jt] = *reinterpret_cast<const bf16x8*>(&Ks[cur][jt*16 + r15][g*8]);
      kf1[jt] = *reinterpret_cast<const bf16x8*>(&Ks[cur][jt*16 + r15][32 + g*8]);
    }
    bf16x8 vf[4][2];
    #pragma unroll
    for (int et=0;et<4;et++)
      #pragma unroll
      for (int p=0;p<2;p++)
        vf[et][p] = *reinterpret_cast<const bf16x8*>(&Vs[cur][et*16 + r15][p*32 + g*8]);

    f32x4 sc[2][4];
    #pragma unroll
    for (int sub=0; sub<2; sub++)
      #pragma unroll
      for (int jt=0;jt<4;jt++){
        f32x4 t = f32x4{0.f,0.f,0.f,0.f};
        t = MFMA_16x16x32(kf0[jt], qf[sub][0], t);
        t = MFMA_16x16x32(kf1[jt], qf[sub][1], t);
        sc[sub][jt] = t;
      }

    bf16x4 pa[2][4];
    #pragma unroll
    for (int sub=0; sub<2; sub++){
      float tmax = sc[sub][0][0];
      #pragma unroll
      for (int jt=0;jt<4;jt++)
        #pragma unroll
        for (int r=0;r<4;r++) tmax = fmaxf(tmax, sc[sub][jt][r]);
      tmax = fmaxf(tmax, __shfl_xor(tmax, 16));
      tmax = fmaxf(tmax, __shfl_xor(tmax, 32));
      if (!__all(tmax <= mst[sub] + 8.0f)){
        float mn  = fmaxf(mst[sub], tmax);
        float fac = exp2f(mst[sub] - mn);
        mst[sub] = mn;
        lst[sub] *= fac;
        float fo0 = __shfl(fac, 4*g+0), fo1 = __shfl(fac, 4*g+1);
        float fo2 = __shfl(fac, 4*g+2), fo3 = __shfl(fac, 4*g+3);
        #pragma unroll
        for (int et=0;et<4;et++){
          o[sub][et][0] *= fo0; o[sub][et][1] *= fo1;
          o[sub][et][2] *= fo2; o[sub][et][3] *= fo3;
        }
      }
      float ps = 0.f;
      #pragma unroll
      for (int ks=0;ks<4;ks++){
        float p0 = exp2f(sc[sub][ks][0] - mst[sub]);
        float p1 = exp2f(sc[sub][ks][1] - mst[sub]);
        float p2 = exp2f(sc[sub][ks][2] - mst[sub]);
        float p3 = exp2f(sc[sub][ks][3] - mst[sub]);
        ps += (p0 + p1) + (p2 + p3);
        pa[sub][ks][0] = (__bf16)p0; pa[sub][ks][1] = (__bf16)p1;
        pa[sub][ks][2] = (__bf16)p2; pa[sub][ks][3] = (__bf16)p3;
      }
      lst[sub] += ps;
    }

    if (hasNext){
      int nxt = cur ^ 1;
      *reinterpret_cast<uint4*>(&Ks[nxt][row0][seg0*8]) = k0v;
      *reinterpret_cast<uint4*>(&Ks[nxt][row1][seg1*8]) = k1v;
      *reinterpret_cast<uint2*>(&Vs[nxt][row0][vcol0])     = uint2{v0v.x, v0v.y};
      *reinterpret_cast<uint2*>(&Vs[nxt][row0][vcol0 + 8]) = uint2{v0v.z, v0v.w};
      *reinterpret_cast<uint2*>(&Vs[nxt][row1][vcol0])     = uint2{v1v.x, v1v.y};
      *reinterpret_cast<uint2*>(&Vs[nxt][row1][vcol0 + 8]) = uint2{v1v.z, v1v.w};
    }

    #pragma unroll
    for (int sub=0; sub<2; sub++)
      #pragma unroll
      for (int et=0;et<4;et++)
        #pragma unroll
        for (int ks=0;ks<4;ks++){
          bf16x8 vv = vf[et][ks>>1];
          bf16x4 vq = (ks & 1) ? bf16x4{vv[4],vv[5],vv[6],vv[7]}
                               : bf16x4{vv[0],vv[1],vv[2],vv[3]};
          o[sub][et] = MFMA16(pa[sub][ks], vq, o[sub][et]);
        }

    __syncthreads();
    cur ^= 1;
  }

  const bool direct = (gridDim.y == 1);
  const int b = bh/NH, h = bh - b*NH;
  const size_t pbase = (size_t)blockIdx.y * RTOT + bh*SS;
  #pragma unroll
  for (int sub=0; sub<2; sub++){
    float lv = lst[sub];
    lv += __shfl_xor(lv, 16);
    lv += __shfl_xor(lv, 32);
    if (direct){
      float linv = 1.0f / lv;
      float li0 = __shfl(linv, 4*g+0), li1 = __shfl(linv, 4*g+1);
      float li2 = __shfl(linv, 4*g+2), li3 = __shfl(linv, 4*g+3);
      float li[4] = {li0, li1, li2, li3};
      #pragma unroll
      for (int r=0;r<4;r++){
        int s = q0 + sub*16 + 4*g + r;
        #pragma unroll
        for (int et=0;et<4;et++)
          AO[((size_t)(b*SS + s))*DM + h*HD + et*16 + r15] = (__bf16)(o[sub][et][r]*li[r]);
      }
    } else {
      if (g == 0){
        mP[pbase + q0 + sub*16 + r15] = mst[sub];
        lP[pbase + q0 + sub*16 + r15] = lv;
      }
      #pragma unroll
      for (int r=0;r<4;r++){
        size_t rid = pbase + q0 + sub*16 + 4*g + r;
        #pragma unroll
        for (int et=0;et<4;et++)
          oP[rid*HD + et*16 + r15] = o[sub][et][r];
      }
    }
  }
}

// merge partials -> AO bf16. One thread = 4 elems of one row.
__global__ __launch_bounds__(256) void k_merge(
    const float* __restrict__ oP, const float* __restrict__ mP,
    const float* __restrict__ lP, __bf16* __restrict__ AO, int nsplit)
{
  int t = blockIdx.x*256 + threadIdx.x;
  int rid = t >> 4, e0 = (t & 15)*4;
  int bh = rid >> 11, s = rid & 2047;
  int b = bh/NH, h = bh - b*NH;

  float M = -1.0e30f;
  for (int sp=0; sp<nsplit; sp++) M = fmaxf(M, mP[(size_t)sp*RTOT + rid]);
  float lsum = 0.f;
  float acc[4] = {0.f,0.f,0.f,0.f};
  for (int sp=0; sp<nsplit; sp++){
    float wgt = exp2f(mP[(size_t)sp*RTOT + rid] - M);
    lsum += lP[(size_t)sp*RTOT + rid] * wgt;
    float4 v = *reinterpret_cast<const float4*>(&oP[((size_t)sp*RTOT + rid)*HD + e0]);
    acc[0] += v.x*wgt; acc[1] += v.y*wgt; acc[2] += v.z*wgt; acc[3] += v.w*wgt;
  }
  float inv = 1.0f/lsum;
  size_t base = ((size_t)(b*SS + s))*DM + h*HD + e0;
  #pragma unroll
  for (int j=0;j<4;j++) AO[base + j] = (__bf16)(acc[j]*inv);
}

// ---------------- launch ----------------
extern "C" void kernel_launch(void* const* d_in, const int* in_sizes, int n_in,
                              void* d_out, int out_size, void* d_ws, size_t ws_size,
                              hipStream_t stream) {
  const float* x  = (const float*)d_in[0];
  const float* Wq = (const float*)d_in[1];
  const float* Wk = (const float*)d_in[2];
  const float* Wv = (const float*)d_in[3];
  const float* bq = (const float*)d_in[4];
  const float* bk = (const float*)d_in[5];
  const float* bv = (const float*)d_in[6];
  const float* Wo = (const float*)d_in[7];
  const float* bo = (const float*)d_in[8];
  float* out = (float*)d_out;

  char* ws = (char*)d_ws;
  size_t off = 0;
  auto alloc = [&](size_t bytes) -> void* {
    void* p = ws + off;
    off += (bytes + 255) & ~size_t(255);
    return p;
  };
  __bf16* xb   = (__bf16*)alloc((size_t)NR*DM*2);
  __bf16* wt   = (__bf16*)alloc((size_t)NC*DM*2);
  float*  bqkv = (float*) alloc((size_t)NC*4);
  __bf16* wot  = (__bf16*)alloc((size_t)DM*DM*2);
  __bf16* qb2  = (__bf16*)alloc((size_t)BB*NH*SS*HD*2);
  __bf16* kb2  = (__bf16*)alloc((size_t)BB*NH*SS*HD*2);
  __bf16* vt2  = (__bf16*)alloc((size_t)BB*NH*SS*HD*2);
  __bf16* aob  = (__bf16*)alloc((size_t)NR*DM*2);
  float*  oP   = (float*) alloc((size_t)2*RTOT*HD*4);
  float*  mP   = (float*) alloc((size_t)2*RTOT*4);
  float*  lP   = (float*) alloc((size_t)2*RTOT*4);
  const int nsplit = (off <= ws_size) ? 2 : 1;   // fall back to direct store

  k_prep_x   <<<(NR*DM)/(4*256), 256, 0, stream>>>(x, xb);
  k_prep_wqkv<<<3*12*12, 256, 0, stream>>>(Wq, Wk, Wv, wt);
  k_prep_wo  <<<12*12, 256, 0, stream>>>(Wo, wot);
  k_prep_bias<<<(NC+255)/256, 256, 0, stream>>>(bq, bk, bv, bqkv);

  k_gemm<128,0><<<(NR/128)*(NC/128), 256, 0, stream>>>(
      xb, wt, bqkv, nullptr, qb2, kb2, vt2, NR, NC);

  dim3 agrid(BB*NH*(SS/128), nsplit);
  k_attn<<<agrid, 256, 0, stream>>>(qb2, kb2, vt2, oP, mP, lP, aob, SS/nsplit);
  if (nsplit > 1)
    k_merge<<<(RTOT*16)/256, 256, 0, stream>>>(oP, mP, lP, aob, nsplit);

  k_gemm<64,1><<<(NR/64)*(DM/128), 256, 0, stream>>>(
      aob, wot, bo, out, nullptr, nullptr, nullptr, NR, DM);
}